// Round 9
// baseline (128.785 us; speedup 1.0000x reference)
//
#include <hip/hip_runtime.h>
#include <hip/hip_bf16.h>

#define CCH 512
#define TTT 1024
#define BBB 8
#define NGRP 32
#define CPG 16
#define NHEAD 8
#define CHD 64
#define O_QKV 1536

typedef __attribute__((ext_vector_type(8))) short bf16x8;
typedef __attribute__((ext_vector_type(4))) short s16x4;
typedef __attribute__((ext_vector_type(4))) float f32x4;

__device__ __forceinline__ float us2f(unsigned short u) {
  union { unsigned int i; float f; } p; p.i = ((unsigned int)u) << 16; return p.f;
}
__device__ __forceinline__ unsigned short f2us(float f) {
  __hip_bfloat16 b = __float2bfloat16(f);
  return *reinterpret_cast<unsigned short*>(&b);
}
__device__ __forceinline__ bf16x8 cat8(s16x4 a, s16x4 b) {
  bf16x8 r;
  r[0] = a[0]; r[1] = a[1]; r[2] = a[2]; r[3] = a[3];
  r[4] = b[0]; r[5] = b[1]; r[6] = b[2]; r[7] = b[3];
  return r;
}
__device__ __forceinline__ float hmax4(f32x4 v) {
  return fmaxf(fmaxf(v[0], v[1]), fmaxf(v[2], v[3]));
}
__device__ __forceinline__ unsigned int pk2(float lo, float hi) {
  return ((unsigned int)f2us(hi) << 16) | (unsigned int)f2us(lo);
}

// Packed layout for a logical [R rows][K cols] bf16 matrix consumed as MFMA frags:
//   subtile (rt=row/16, kt=k/16) base = (rt*(K/16)+kt)*256
//   within: ((k%16)/4)*64 + (row%16)*4 + (k%4)

// ---------------- W f32 -> packed bf16 (qkv_w then proj_w, one launch) ----------------
__global__ __launch_bounds__(256) void wpack_kernel(
    const float* __restrict__ wq, const float* __restrict__ wp,
    unsigned short* __restrict__ op, int nslot)
{
  const int s = blockIdx.x * 256 + threadIdx.x;   // one ushort4 slot
  if (s >= nslot) return;
  const int u = s & 63, sub = s >> 6;
  const int kt = sub & 31, rt = sub >> 5;         // K = 512 -> 32 kt
  const int lg = u >> 4, lr = u & 15;
  const int row = rt * 16 + lr;
  const float* src = (row < O_QKV) ? &wq[(size_t)row * CCH]
                                   : &wp[(size_t)(row - O_QKV) * CCH];
  float4 v = *reinterpret_cast<const float4*>(&src[kt * 16 + lg * 4]);
  ushort4 r;
  r.x = f2us(v.x); r.y = f2us(v.y); r.z = f2us(v.z); r.w = f2us(v.w);
  reinterpret_cast<ushort4*>(op)[s] = r;
}

// ---------------- GroupNorm: f32 [b][c][t] -> packed H (row=t, k=c) ----------------
__global__ __launch_bounds__(256) void gn_kernel(
    const float* __restrict__ x,
    const float* __restrict__ gw,
    const float* __restrict__ gb,
    unsigned short* __restrict__ hP)
{
  __shared__ __align__(16) float xs[16][1028];
  const int bg = blockIdx.x;
  const int bb = bg >> 5, g = bg & 31;
  const size_t base = ((size_t)bb * CCH + (size_t)g * CPG) * TTT;
  const float4* xv = reinterpret_cast<const float4*>(x + base);
  const int tid = threadIdx.x;

  float s = 0.f, q = 0.f;
  for (int i = tid; i < 4096; i += 256) {
    float4 u = xv[i];
    const int c = i >> 8, t4 = (i & 255) << 2;
    *reinterpret_cast<float4*>(&xs[c][t4]) = u;
    s += (u.x + u.y) + (u.z + u.w);
    q += u.x * u.x + u.y * u.y + u.z * u.z + u.w * u.w;
  }
  #pragma unroll
  for (int off = 32; off > 0; off >>= 1) {
    s += __shfl_down(s, off);
    q += __shfl_down(q, off);
  }
  __shared__ float red[10];
  const int wid = tid >> 6, lane = tid & 63;
  if (lane == 0) { red[wid] = s; red[4 + wid] = q; }
  __syncthreads();
  if (tid == 0) {
    float S = red[0] + red[1] + red[2] + red[3];
    float Q = red[4] + red[5] + red[6] + red[7];
    float mu = S * (1.f / 16384.f);
    float var = Q * (1.f / 16384.f) - mu * mu;
    red[8] = mu;
    red[9] = rsqrtf(var + 1e-5f);
  }
  __syncthreads();
  const float mu = red[8], rstd = red[9];
  float wsc[16], wbs[16];
  #pragma unroll
  for (int cc = 0; cc < 16; cc++) {
    wsc[cc] = gw[g * CPG + cc] * rstd;
    wbs[cc] = gb[g * CPG + cc] - mu * wsc[cc];
  }
  for (int tt = tid; tt < 1024; tt += 256) {
    float v[16];
    #pragma unroll
    for (int cc = 0; cc < 16; cc++)
      v[cc] = fmaf(xs[cc][tt], wsc[cc], wbs[cc]);
    unsigned short* dst = &hP[(size_t)bb * 524288 + ((size_t)((tt >> 4) * 32 + g)) * 256 + (tt & 15) * 4];
    #pragma unroll
    for (int l2 = 0; l2 < 4; l2++) {
      ushort4 st;
      st.x = f2us(v[l2 * 4 + 0]);
      st.y = f2us(v[l2 * 4 + 1]);
      st.z = f2us(v[l2 * 4 + 2]);
      st.w = f2us(v[l2 * 4 + 3]);
      *reinterpret_cast<ushort4*>(&dst[l2 * 64]) = st;
    }
  }
}

// ---------------- LDS-free packed MFMA GEMM (unchanged) ----------------
template<int MODE>
__global__ __launch_bounds__(256) void gemm_p(
    const unsigned short* __restrict__ Ap,
    const unsigned short* __restrict__ Bp,
    const float* __restrict__ bias,
    const float* __restrict__ resid,
    unsigned short* __restrict__ oq,
    unsigned short* __restrict__ ok,
    unsigned short* __restrict__ ov,
    float* __restrict__ of,
    const int O)
{
  const int tid = threadIdx.x;
  const int bz = blockIdx.z, o0 = blockIdx.y << 7, t0 = blockIdx.x << 7;
  const int lane = tid & 63, w = tid >> 6;
  const int lg = lane >> 4, lr = lane & 15;
  const int wr = w >> 1, wc = w & 1;
  const int laneoff = (lg >> 1) * 256 + (lg & 1) * 128 + lr * 4;

  const unsigned short* Ab = Ap + (size_t)(((o0 >> 4) + wr * 4) * 32) * 256 + laneoff;
  const unsigned short* Bb = Bp + (size_t)bz * 524288
      + (size_t)(((t0 >> 4) + wc * 4) * 32) * 256 + laneoff;

  f32x4 acc[4][4];
  #pragma unroll
  for (int m = 0; m < 4; m++)
    #pragma unroll
    for (int n = 0; n < 4; n++) acc[m][n] = f32x4{0.f, 0.f, 0.f, 0.f};

  #pragma unroll 2
  for (int kb = 0; kb < 32; kb += 2) {
    bf16x8 af[4], bf[4];
    #pragma unroll
    for (int m = 0; m < 4; m++) {
      const unsigned short* p = Ab + (m * 32 + kb) * 256;
      af[m] = cat8(*reinterpret_cast<const s16x4*>(p),
                   *reinterpret_cast<const s16x4*>(p + 64));
    }
    #pragma unroll
    for (int n = 0; n < 4; n++) {
      const unsigned short* p = Bb + (n * 32 + kb) * 256;
      bf[n] = cat8(*reinterpret_cast<const s16x4*>(p),
                   *reinterpret_cast<const s16x4*>(p + 64));
    }
    #pragma unroll
    for (int n = 0; n < 4; n++)
      #pragma unroll
      for (int m = 0; m < 4; m++)
        acc[m][n] = __builtin_amdgcn_mfma_f32_16x16x32_bf16(af[m], bf[n], acc[m][n], 0, 0, 0);
  }

  if (MODE == 0) {
    const int a = (o0 >> 6) + wr;
    float bi[4][4];
    #pragma unroll
    for (int m = 0; m < 4; m++)
      #pragma unroll
      for (int r = 0; r < 4; r++)
        bi[m][r] = bias[a * 64 + m * 16 + lg * 4 + r];
    const int head = a / 3, part = a - head * 3;
    const size_t bho = ((size_t)bz * NHEAD + head) << 16;
    if (part < 2) {
      unsigned short* dst = (part == 0 ? oq : ok) + bho;
      #pragma unroll
      for (int n = 0; n < 4; n++) {
        const int rt4 = ((t0 >> 4) + wc * 4 + n) * 4;
        #pragma unroll
        for (int m = 0; m < 4; m++) {
          ushort4 st;
          st.x = f2us(acc[m][n][0] + bi[m][0]);
          st.y = f2us(acc[m][n][1] + bi[m][1]);
          st.z = f2us(acc[m][n][2] + bi[m][2]);
          st.w = f2us(acc[m][n][3] + bi[m][3]);
          *reinterpret_cast<ushort4*>(&dst[((size_t)(rt4 + m) << 8) + lg * 64 + lr * 4]) = st;
        }
      }
    } else {
      unsigned short* dst = ov + bho;
      const int vsub = (lr >> 2) * 64 + (lr & 3);
      #pragma unroll
      for (int m = 0; m < 4; m++)
        #pragma unroll
        for (int n = 0; n < 4; n++) {
          const int kt = (t0 >> 4) + wc * 4 + n;
          unsigned short* q = &dst[((size_t)(m * 64 + kt) << 8) + vsub];
          #pragma unroll
          for (int r = 0; r < 4; r++)
            q[(lg * 4 + r) * 4] = f2us(acc[m][n][r] + bi[m][r]);
        }
    }
  } else {
    #pragma unroll
    for (int m = 0; m < 4; m++)
      #pragma unroll
      for (int r = 0; r < 4; r++) {
        const int o = o0 + wr * 64 + m * 16 + lg * 4 + r;
        const float bv = bias[o];
        const size_t rowbase = ((size_t)bz * O + o) * TTT + t0 + wc * 64 + lr;
        #pragma unroll
        for (int n = 0; n < 4; n++) {
          const size_t idx = rowbase + n * 16;
          of[idx] = acc[m][n][r] + bv + resid[idx];
        }
      }
  }
}

// ---------------- all-register flash attention ----------------
// QK^T = mfma(K_perm, Q): K rows fed permuted (sigma) so lane (lg,lr) ends up
// holding exactly the s-values its PV B-frag needs:
//   sc[0][r]=S[8lg+r], sc[1][r]=S[8lg+4+r], sc[2][r]=S[32+8lg+r], sc[3][r]=S[32+8lg+4+r]
// P never touches LDS: exp2 results pack to bf16 pairs -> B-frags in registers.
// 1-deep pipeline: QK(i+1) issues between softmax(i) and PV(i).
__global__ __launch_bounds__(512, 4) void attn_p(
    const unsigned short* __restrict__ qP,
    const unsigned short* __restrict__ kP,
    const unsigned short* __restrict__ vP,
    unsigned short* __restrict__ avP)
{
  const int bid = blockIdx.x;                    // 0..511
  const int bh = (bid & 7) * 8 + (bid >> 6);     // XCD-bijective
  const int t0 = ((bid >> 3) & 7) << 7;          // 8 t-blocks of 128 queries
  const int b = bh >> 3, hh = bh & 7;
  const int tid = threadIdx.x;
  const int lane = tid & 63, w = tid >> 6;       // w = 0..7
  const int lg = lane >> 4, lr = lane & 15;
  const int laneoff = (lg >> 1) * 256 + (lg & 1) * 128 + lr * 4;

  const unsigned short* Qb = qP + ((size_t)bh << 16) + laneoff;
  const unsigned short* Kb = kP + ((size_t)bh << 16);      // laneoff in koff
  const unsigned short* Vb = vP + ((size_t)bh << 16) + laneoff;

  // permuted-row K frag offsets (shorts) per sn
  int koff[4];
  #pragma unroll
  for (int sn = 0; sn < 4; sn++) {
    const int s_local = (sn >> 1) * 32 + (sn & 1) * 4 + ((lr >> 2) << 3) + (lr & 3);
    koff[sn] = (s_local >> 4) * 1024 + (s_local & 15) * 4
             + (lg >> 1) * 256 + (lg & 1) * 128;
  }

  // Q B-frag (col=t=lr, k=c)
  bf16x8 aq[2];
  {
    const unsigned short* qa = Qb + ((t0 >> 2) + w * 4) * 256;
    aq[0] = cat8(*reinterpret_cast<const s16x4*>(qa),
                 *reinterpret_cast<const s16x4*>(qa + 64));
    aq[1] = cat8(*reinterpret_cast<const s16x4*>(qa + 512),
                 *reinterpret_cast<const s16x4*>(qa + 512 + 64));
  }

  f32x4 opv[4];
  #pragma unroll
  for (int cn = 0; cn < 4; cn++) opv[cn] = f32x4{0.f, 0.f, 0.f, 0.f};
  float mrow = -1e30f, lrow = 0.f;
  const float SC2 = 0.125f * 1.44269504f;

  bf16x8 kf[4][2];
  f32x4 sc[4];

#define LOADK(tile) do {                                                   \
    const unsigned short* tb_ = Kb + (tile) * 4096;                        \
    _Pragma("unroll") for (int sn_ = 0; sn_ < 4; sn_++)                    \
      _Pragma("unroll") for (int k2_ = 0; k2_ < 2; k2_++) {                \
        const unsigned short* p_ = tb_ + koff[sn_] + k2_ * 512;            \
        kf[sn_][k2_] = cat8(*reinterpret_cast<const s16x4*>(p_),           \
                            *reinterpret_cast<const s16x4*>(p_ + 64));     \
      } } while (0)

#define QKT do {                                                           \
    __builtin_amdgcn_s_setprio(1);                                         \
    _Pragma("unroll") for (int sn_ = 0; sn_ < 4; sn_++) {                  \
      f32x4 t_ = __builtin_amdgcn_mfma_f32_16x16x32_bf16(                  \
          kf[sn_][0], aq[0], f32x4{0.f, 0.f, 0.f, 0.f}, 0, 0, 0);          \
      sc[sn_] = __builtin_amdgcn_mfma_f32_16x16x32_bf16(                   \
          kf[sn_][1], aq[1], t_, 0, 0, 0);                                 \
    }                                                                      \
    __builtin_amdgcn_s_setprio(0); } while (0)

  LOADK(0);
  QKT;
  LOADK(1);

  for (int sbi = 0; sbi < 16; sbi++) {
    // V frags for this tile (A-operand: row=c, k=s) — issue loads early
    bf16x8 bv[4][2];
    #pragma unroll
    for (int cn = 0; cn < 4; cn++)
      #pragma unroll
      for (int k2 = 0; k2 < 2; k2++) {
        const unsigned short* p = Vb + (cn * 64 + sbi * 4 + k2 * 2) * 256;
        bv[cn][k2] = cat8(*reinterpret_cast<const s16x4*>(p),
                          *reinterpret_cast<const s16x4*>(p + 64));
      }

    // ---- lane-local softmax (query t = t0 + w*16 + lr) ----
    float mx = fmaxf(fmaxf(hmax4(sc[0]), hmax4(sc[1])),
                     fmaxf(hmax4(sc[2]), hmax4(sc[3]))) * SC2;
    mx = fmaxf(mx, __shfl_xor(mx, 16));
    mx = fmaxf(mx, __shfl_xor(mx, 32));
    if (!__all(mx <= mrow + 8.f)) {              // defer-max (log2 units)
      const float mn = fmaxf(mrow, mx);
      const float rsc = exp2f(mrow - mn);
      mrow = mn;
      lrow *= rsc;
      #pragma unroll
      for (int cn = 0; cn < 4; cn++)
        #pragma unroll
        for (int r = 0; r < 4; r++) opv[cn][r] *= rsc;
    }

    float e[4][4];
    float rs = 0.f;
    #pragma unroll
    for (int sn = 0; sn < 4; sn++) {
      #pragma unroll
      for (int r = 0; r < 4; r++) {
        e[sn][r] = exp2f(fmaf(sc[sn][r], SC2, -mrow));
      }
      rs += (e[sn][0] + e[sn][1]) + (e[sn][2] + e[sn][3]);
    }
    lrow += rs;

    // pack P B-frags fully in registers (s-order guaranteed by K row perm)
    union U8 { unsigned int u[4]; bf16x8 v; };
    U8 a0, a1;
    a0.u[0] = pk2(e[0][0], e[0][1]); a0.u[1] = pk2(e[0][2], e[0][3]);
    a0.u[2] = pk2(e[1][0], e[1][1]); a0.u[3] = pk2(e[1][2], e[1][3]);
    a1.u[0] = pk2(e[2][0], e[2][1]); a1.u[1] = pk2(e[2][2], e[2][3]);
    a1.u[2] = pk2(e[3][0], e[3][1]); a1.u[3] = pk2(e[3][2], e[3][3]);
    const bf16x8 pb0 = a0.v, pb1 = a1.v;

    // issue next tile's QK (sc already consumed) + K prefetch
    if (sbi < 15) {
      QKT;
      LOADK(sbi + 2 < 16 ? sbi + 2 : 0);
    }

    // PV
    __builtin_amdgcn_s_setprio(1);
    #pragma unroll
    for (int cn = 0; cn < 4; cn++) {
      opv[cn] = __builtin_amdgcn_mfma_f32_16x16x32_bf16(bv[cn][0], pb0, opv[cn], 0, 0, 0);
      opv[cn] = __builtin_amdgcn_mfma_f32_16x16x32_bf16(bv[cn][1], pb1, opv[cn], 0, 0, 0);
    }
    __builtin_amdgcn_s_setprio(0);
  }

  // final l reduce across lg groups
  float lt = lrow;
  lt += __shfl_xor(lt, 16);
  lt += __shfl_xor(lt, 32);
  const float linv = 1.f / lt;

  // avP packed (row=t, k=c): subtile (rt = t0/16 + w, kt = hh*4+cn)
  const int rt = (t0 >> 4) + w;
  unsigned short* dst = avP + (size_t)b * 524288;
  #pragma unroll
  for (int cn = 0; cn < 4; cn++) {
    ushort4 o;
    o.x = f2us(opv[cn][0] * linv);
    o.y = f2us(opv[cn][1] * linv);
    o.z = f2us(opv[cn][2] * linv);
    o.w = f2us(opv[cn][3] * linv);
    *reinterpret_cast<ushort4*>(&dst[((size_t)(rt * 32 + hh * 4 + cn) << 8) + lg * 64 + lr * 4]) = o;
  }
#undef LOADK
#undef QKT
}

extern "C" void kernel_launch(void* const* d_in, const int* in_sizes, int n_in,
                              void* d_out, int out_size, void* d_ws, size_t ws_size,
                              hipStream_t stream) {
  const float* x      = (const float*)d_in[0];
  const float* gn_w   = (const float*)d_in[1];
  const float* gn_b   = (const float*)d_in[2];
  const float* qkv_w  = (const float*)d_in[3];
  const float* qkv_b  = (const float*)d_in[4];
  const float* proj_w = (const float*)d_in[5];
  const float* proj_b = (const float*)d_in[6];
  float* out = (float*)d_out;

  const size_t HT = (size_t)BBB * TTT * CCH;
  const size_t QK = (size_t)BBB * NHEAD * TTT * CHD;
  unsigned short* hP  = (unsigned short*)d_ws;
  unsigned short* vP  = hP + HT;
  unsigned short* avP = vP + QK;
  unsigned short* wq  = avP + HT;
  unsigned short* wp  = wq + (size_t)O_QKV * CCH;
  unsigned short* qPd = (unsigned short*)d_out;   // scratch in d_out (rewritten)
  unsigned short* kPd = qPd + QK;

  const int nslot = (O_QKV + CCH) * CCH / 4;
  wpack_kernel<<<dim3(nslot / 256), 256, 0, stream>>>(qkv_w, proj_w, wq, nslot);
  gn_kernel<<<dim3(BBB * NGRP), 256, 0, stream>>>(x, gn_w, gn_b, hP);
  gemm_p<0><<<dim3(TTT / 128, O_QKV / 128, BBB), 256, 0, stream>>>(
      wq, hP, qkv_b, nullptr, qPd, kPd, vP, nullptr, O_QKV);
  attn_p<<<dim3(512), 512, 0, stream>>>(qPd, kPd, vP, avP);
  gemm_p<1><<<dim3(TTT / 128, CCH / 128, BBB), 256, 0, stream>>>(
      wp, avP, proj_b, x, nullptr, nullptr, nullptr, out, CCH);
}